// Round 7
// baseline (387.464 us; speedup 1.0000x reference)
//
#include <hip/hip_runtime.h>
#include <math.h>

#define P 45
#define N_ITER 20

typedef float v2f __attribute__((ext_vector_type(2)));
typedef float v4f __attribute__((ext_vector_type(4)));

// Pure-VALU cross-lane add via DPP.
template<int CTRL>
__device__ __forceinline__ float dpp_add(float x) {
    int xi = __builtin_bit_cast(int, x);
    int yi = __builtin_amdgcn_update_dpp(0, xi, CTRL, 0xF, 0xF, true);
    return x + __builtin_bit_cast(float, yi);
}

// Full wave64 sum, broadcast via readlane -> SGPR.
__device__ __forceinline__ float wave_sum_bcast(float x) {
    x = dpp_add<0x111>(x); // row_shr:1
    x = dpp_add<0x112>(x); // row_shr:2
    x = dpp_add<0x114>(x); // row_shr:4
    x = dpp_add<0x118>(x); // row_shr:8
    x = dpp_add<0x142>(x); // row_bcast:15
    x = dpp_add<0x143>(x); // row_bcast:31
    int si = __builtin_amdgcn_readlane(__builtin_bit_cast(int, x), 63);
    return __builtin_bit_cast(float, si);
}

__device__ __forceinline__ float clamp015(float x) {
    return __builtin_amdgcn_fmed3f(x, 0.0f, 0.15f);
}

__global__ __launch_bounds__(64) void drb_kernel(
    const float* __restrict__ sigma,
    const float* __restrict__ beta,
    const float* __restrict__ w_prev,
    const float* __restrict__ lls,
    const float* __restrict__ llt,
    float* __restrict__ out)
{
    const int b    = blockIdx.x;
    const int lane = threadIdx.x;
    const bool active = lane < P;
    const bool ones   = (lane == P);   // lane 45: all-ones row -> acc = sum(c)

    const float lam_s  = expf(lls[0]);
    const float lam_t2 = 2.0f * expf(llt[0]);

    float base = 0.0f;
    if (active) {
        base = -beta[(size_t)b * P + lane]
               - lam_t2 * w_prev[(size_t)b * P + lane];
    }

    // sigma is bitwise symmetric: row i == column i -> coalesced column loads.
    const int cidx = active ? lane : 0;
    const float* sp = sigma + (size_t)b * (P * P) + cidx;

    // Part A rows: floats 0..23 as 12 float2 (paired with uniform LDS b128
    // broadcast). Part B rows: floats 24..44 (paired with readlane broadcast).
    v2f rowA[12];
    #pragma unroll
    for (int k = 0; k < 12; ++k) {
        float lo = sp[(size_t)(2 * k)     * P];
        float hi = sp[(size_t)(2 * k + 1) * P];
        v2f t;
        t.x = active ? lo : (ones ? 1.0f : 0.0f);
        t.y = active ? hi : (ones ? 1.0f : 0.0f);
        rowA[k] = t;
    }
    float rowB[21];
    #pragma unroll
    for (int k = 0; k < 21; ++k) {
        float v = sp[(size_t)(24 + k) * P];
        rowB[k] = active ? v : (ones ? 1.0f : 0.0f);
    }
    #pragma unroll
    for (int k = 0; k < 12; ++k) asm volatile("" : "+v"(rowA[k]));
    #pragma unroll
    for (int k = 0; k < 21; ++k) asm volatile("" : "+v"(rowB[k]));

    // Per-wave double-buffered w slots. Single-wave workgroup: LDS ops are
    // in-order within a wave, so no barrier is needed between the write and
    // the uniform reads of the same buffer.
    __shared__ __align__(16) float sh[128];

    float c = active ? (float)(1.0 / 45.0) : 0.0f;

    #pragma unroll
    for (int it = 0; it < N_ITER; ++it) {
        float* shb = sh + ((it & 1) << 6);
        shb[lane] = c;   // lanes >= P publish exact zeros

        // --- Part B: broadcast w[24..44] via readlane (VALU pipe) ---
        const int ci = __builtin_bit_cast(int, c);
        float accB0 = 0.0f, accB1 = 0.0f, accB2 = 0.0f;
        #pragma unroll
        for (int k = 0; k < 21; k += 3) {
            float w0 = __builtin_bit_cast(float, __builtin_amdgcn_readlane(ci, 24 + k));
            float w1 = __builtin_bit_cast(float, __builtin_amdgcn_readlane(ci, 25 + k));
            float w2 = __builtin_bit_cast(float, __builtin_amdgcn_readlane(ci, 26 + k));
            accB0 = fmaf(rowB[k],     w0, accB0);
            accB1 = fmaf(rowB[k + 1], w1, accB1);
            accB2 = fmaf(rowB[k + 2], w2, accB2);
        }

        // --- Part A: broadcast w[0..23] via uniform LDS b128 (LDS pipe) ---
        const v4f* shv = (const v4f*)shb;
        v2f accA0; accA0.x = 0.0f; accA0.y = 0.0f;
        v2f accA1 = accA0;
        #pragma unroll
        for (int k = 0; k < 6; ++k) {
            v4f q = shv[k];                     // floats 4k..4k+3 (uniform addr)
            v2f lo; lo.x = q.x; lo.y = q.y;
            v2f hi; hi.x = q.z; hi.y = q.w;
            accA0 = __builtin_elementwise_fma(rowA[2 * k],     lo, accA0);
            accA1 = __builtin_elementwise_fma(rowA[2 * k + 1], hi, accA1);
        }
        v2f amA = accA0 + accA1;
        const float acc = (amA.x + amA.y) + ((accB0 + accB1) + accB2);

        // sum(c) from lane 45's ones-row dot product.
        const float s2 = __builtin_bit_cast(float,
            __builtin_amdgcn_readlane(__builtin_bit_cast(int, acc), P));
        const float r = __builtin_amdgcn_rcpf(s2 + 1e-8f);

        // w_i = c_i * r;  Sw_i = r * acc
        const float t = c * r;
        float g = fmaf(lam_t2, t, base);
        g += (c > 0.0f) ? lam_s : 0.0f;
        g = fmaf(r + r, acc, g);
        const float x = fmaf(-0.05f, g, t);

        // projection: clip, renorm, clip; final renorm deferred.
        const float a  = clamp015(x);
        const float s1 = wave_sum_bcast(a);
        const float r1 = __builtin_amdgcn_rcpf(s1 + 1e-8f);
        c = clamp015(a * r1);
        // lane 45: acc = sum(c) -> x < 0 -> stays exactly 0. Lanes 46..63: 0.
    }

    // Epilogue: final deferred normalize.
    const float sf = wave_sum_bcast(c);
    const float rf = __builtin_amdgcn_rcpf(sf + 1e-8f);
    if (active) out[(size_t)b * P + lane] = c * rf;
}

extern "C" void kernel_launch(void* const* d_in, const int* in_sizes, int n_in,
                              void* d_out, int out_size, void* d_ws, size_t ws_size,
                              hipStream_t stream) {
    const float* sigma  = (const float*)d_in[0];
    const float* beta   = (const float*)d_in[1];
    const float* w_prev = (const float*)d_in[2];
    const float* lls    = (const float*)d_in[3];
    const float* llt    = (const float*)d_in[4];
    float* out = (float*)d_out;

    const int B = in_sizes[1] / P;   // 32768
    drb_kernel<<<B, 64, 0, stream>>>(sigma, beta, w_prev, lls, llt, out);
}